// Round 23
// baseline (245.605 us; speedup 1.0000x reference)
//
#include <hip/hip_runtime.h>
#include <hip/hip_bf16.h>

static constexpr int Bb  = 2;
static constexpr int Tt  = 2048;
static constexpr int Cc  = 1024;
static constexpr int Hh  = 16;
static constexpr int HDi = 64;
static constexpr int HID = 1365;
static constexpr int HIDP = 1408;      // HID padded to multiple of 128
static constexpr int Mm  = Bb * Tt;    // 4096 rows

typedef unsigned short u16;
typedef __attribute__((ext_vector_type(8))) short bf16x8;
typedef __attribute__((ext_vector_type(4))) float f32x4;
typedef __attribute__((ext_vector_type(8))) unsigned short u16x8;
typedef __attribute__((ext_vector_type(4))) unsigned short u16x4;

__device__ inline u16 f2bf(float f) {
    unsigned u = __builtin_bit_cast(unsigned, f);
    u += 0x7fffu + ((u >> 16) & 1u);
    return (u16)(u >> 16);
}

__device__ inline unsigned cvtpk(float lo, float hi) {
    unsigned r;
    asm("v_cvt_pk_bf16_f32 %0, %1, %2" : "=v"(r) : "v"(lo), "v"(hi));
    return r;
}

__device__ inline float vexp2(float x) {   // raw v_exp_f32 (2^x)
    float r;
    asm("v_exp_f32 %0, %1" : "=v"(r) : "v"(x));
    return r;
}

__device__ inline void gl16(const void* g, void* l) {
    __builtin_amdgcn_global_load_lds(
        (const __attribute__((address_space(1))) unsigned*)g,
        (__attribute__((address_space(3))) unsigned*)l, 16, 0, 0);
}

// ---------------- LayerNorm: one row (C=1024) per block; OUTBF: bf16 out ----------------
template<int OUTBF>
__global__ __launch_bounds__(256) void ln_k(const float* __restrict__ x,
                                            const float* __restrict__ g,
                                            const float* __restrict__ b,
                                            void* __restrict__ yv) {
    int row = blockIdx.x;
    int tid = threadIdx.x;
    const float4* xr = (const float4*)(x + (size_t)row * Cc);
    float4 v = xr[tid];
    float s  = v.x + v.y + v.z + v.w;
    float ss = v.x*v.x + v.y*v.y + v.z*v.z + v.w*v.w;
    __shared__ float rs[256], rq[256];
    rs[tid] = s; rq[tid] = ss;
    __syncthreads();
    for (int o = 128; o > 0; o >>= 1) {
        if (tid < o) { rs[tid] += rs[tid+o]; rq[tid] += rq[tid+o]; }
        __syncthreads();
    }
    float mean = rs[0] * (1.f/Cc);
    float var  = rq[0] * (1.f/Cc) - mean*mean;
    float inv  = rsqrtf(var + 1e-5f);
    float4 gv = ((const float4*)g)[tid];
    float4 bv = ((const float4*)b)[tid];
    float o0 = (v.x-mean)*inv*gv.x + bv.x;
    float o1 = (v.y-mean)*inv*gv.y + bv.y;
    float o2 = (v.z-mean)*inv*gv.z + bv.z;
    float o3 = (v.w-mean)*inv*gv.w + bv.w;
    if (OUTBF) {
        u16x4 o4 = { f2bf(o0), f2bf(o1), f2bf(o2), f2bf(o3) };
        ((u16x4*)((u16*)yv + (size_t)row * Cc))[tid] = o4;
    } else {
        float4 o4 = { o0, o1, o2, o3 };
        ((float4*)((float*)yv + (size_t)row * Cc))[tid] = o4;
    }
}

// ---------------- merged prep + LN(query)+LN(key) ----------------
__global__ __launch_bounds__(256) void prepln_k(const float* __restrict__ query,
                                                const float* __restrict__ key,
                                                const float* __restrict__ gq, const float* __restrict__ bq,
                                                const float* __restrict__ gk, const float* __restrict__ bk,
                                                u16* __restrict__ qn, u16* __restrict__ kn,
                                                const float* __restrict__ in_proj_w, u16* __restrict__ wA,
                                                const float* __restrict__ proj_w,  u16* __restrict__ wPb,
                                                const float* __restrict__ w1, u16* __restrict__ w1b,
                                                const float* __restrict__ w2, u16* __restrict__ w2b,
                                                const float* __restrict__ w3, u16* __restrict__ w3b,
                                                const float* __restrict__ out_w, u16* __restrict__ wOt,
                                                const float* __restrict__ out_b, const float* __restrict__ bp,
                                                float* __restrict__ bc,
                                                const float* __restrict__ rel, float* __restrict__ mr) {
    __shared__ float sh[64*65];
    int bid = blockIdx.x, tid = threadIdx.x;
    if (bid < 2*Mm) {
        const float* x; const float* g; const float* bb; u16* y; int r;
        if (bid < Mm) { x = query; g = gq; bb = bq; y = qn; r = bid; }
        else          { x = key;   g = gk; bb = bk; y = kn; r = bid - Mm; }
        float4 v = ((const float4*)(x + (size_t)r * Cc))[tid];
        float s  = v.x + v.y + v.z + v.w;
        float ss = v.x*v.x + v.y*v.y + v.z*v.z + v.w*v.w;
        float* rs = sh; float* rq2 = sh + 256;
        rs[tid] = s; rq2[tid] = ss;
        __syncthreads();
        for (int o = 128; o > 0; o >>= 1) {
            if (tid < o) { rs[tid] += rs[tid+o]; rq2[tid] += rq2[tid+o]; }
            __syncthreads();
        }
        float mean = rs[0] * (1.f/Cc);
        float var  = rq2[0] * (1.f/Cc) - mean*mean;
        float inv  = rsqrtf(var + 1e-5f);
        float4 gv = ((const float4*)g)[tid];
        float4 bv = ((const float4*)bb)[tid];
        u16x4 o4 = { f2bf((v.x-mean)*inv*gv.x + bv.x), f2bf((v.y-mean)*inv*gv.y + bv.y),
                     f2bf((v.z-mean)*inv*gv.z + bv.z), f2bf((v.w-mean)*inv*gv.w + bv.w) };
        ((u16x4*)(y + (size_t)r * Cc))[tid] = o4;
        return;
    }
    bid -= 2*Mm;
    if (bid < 3456) {
        int u = bid * 256 + tid;
        const float* src; u16* dst; int valid;
        if (u < 1536*256)                   { src = in_proj_w; dst = wA;  valid = 3*Cc*Cc; }
        else if ((u -= 1536*256) < 512*256) { src = proj_w;    dst = wPb; valid = Cc*Cc; }
        else if ((u -= 512*256) < 704*256)  { src = w1;        dst = w1b; valid = HID*Cc; }
        else     { u -= 704*256;              src = w2;        dst = w2b; valid = HID*Cc; }
        int e0 = u * 8;
        u16x8 o;
        if (e0 + 8 <= valid) {
            float4 a = *(const float4*)(src + e0);
            float4 b = *(const float4*)(src + e0 + 4);
            o[0]=f2bf(a.x); o[1]=f2bf(a.y); o[2]=f2bf(a.z); o[3]=f2bf(a.w);
            o[4]=f2bf(b.x); o[5]=f2bf(b.y); o[6]=f2bf(b.z); o[7]=f2bf(b.w);
        } else {
            #pragma unroll
            for (int j = 0; j < 8; j++) { int e = e0 + j; o[j] = f2bf(e < valid ? src[e] : 0.f); }
        }
        *(u16x8*)(dst + (size_t)e0) = o;
    } else if (bid < 4160) {
        int idx = (bid - 3456) * 256 + tid;
        int e0 = idx * 8;
        int r = e0 / HIDP, c0 = e0 - r * HIDP;
        u16x8 o;
        #pragma unroll
        for (int j = 0; j < 8; j++) {
            int c = c0 + j;
            o[j] = f2bf(c < HID ? w3[(size_t)r * HID + c] : 0.f);
        }
        *(u16x8*)(w3b + (size_t)e0) = o;
    } else if (bid < 4416) {
        int id = bid - 4160;
        int j0 = (id & 15) * 64, c0 = (id >> 4) * 64;
        #pragma unroll
        for (int i = 0; i < 16; i++) {
            int e = tid + i*256;
            int c = e >> 6, j = e & 63;
            sh[c*65 + j] = out_w[(size_t)(c0 + c) * Cc + j0 + j];
        }
        __syncthreads();
        #pragma unroll
        for (int i = 0; i < 16; i++) {
            int e = tid + i*256;
            int j = e >> 6, c = e & 63;
            wOt[(size_t)(j0 + j) * Cc + c0 + c] = f2bf(sh[c*65 + j]);
        }
    } else if (bid < 5440) {
        int i = bid - 4416;
        float4 w = ((const float4*)(proj_w + (size_t)i * Cc))[tid];
        float4 b = ((const float4*)out_b)[tid];
        float s = w.x*b.x + w.y*b.y + w.z*b.z + w.w*b.w;
        sh[tid] = s; __syncthreads();
        for (int o = 128; o > 0; o >>= 1) {
            if (tid < o) sh[tid] += sh[tid+o];
            __syncthreads();
        }
        if (tid == 0) bc[i] = sh[0] + bp[i];
    } else {
        int j = (bid - 5440) * 256 + tid;
        if (j < 2*Tt - 1) {
            float s = 0.f;
            #pragma unroll
            for (int h = 0; h < Hh; h++) s += rel[(size_t)h * (2*Tt - 1) + j];
            mr[j] = s * (1.f/Hh);
        }
    }
}

// ---------------- bf16 MFMA GEMM 64x128 tile, dbuf + 1 barrier/K-step ----------------
template<int OUTBF, int HASRES, int HASBIAS>
__global__ __launch_bounds__(256) void mgemm64_k(const u16* __restrict__ A,
                                                 const u16* __restrict__ W,
                                                 const float* __restrict__ bias,
                                                 const float* __restrict__ res,
                                                 void* __restrict__ outv,
                                                 int N, int K) {
    __shared__ u16 As[2][64*32];
    __shared__ u16 Ws[2][128*32];
    int bm = blockIdx.y * 64, bn = blockIdx.x * 128;
    int tid = threadIdx.x, w = tid >> 6, l = tid & 63;
    int lr = l & 15, lh = l >> 4;
    int wm = (w >> 1) * 32, wn = (w & 1) * 64;
    f32x4 acc[2][4] = {};

    auto stage = [&](int buf, int kt) {
        {
            int row = tid >> 2, slot = tid & 3;
            int ko = kt + ((slot ^ (row & 3)) << 3);
            gl16(A + (size_t)(bm + row) * K + ko, (char*)As[buf] + tid * 16);
        }
        #pragma unroll
        for (int c = 0; c < 2; c++) {
            int i = c*256 + tid;
            int row = i >> 2, slot = i & 3;
            int ko = kt + ((slot ^ (row & 3)) << 3);
            gl16(W + (size_t)(bn + row) * K + ko, (char*)Ws[buf] + (c*256 + tid) * 16);
        }
    };
    stage(0, 0);
    for (int kt = 0; kt < K; kt += 32) {
        int buf = (kt >> 5) & 1;
        __syncthreads();
        if (kt + 32 < K) stage(buf ^ 1, kt + 32);
        bf16x8 af[2], wf[4];
        #pragma unroll
        for (int f = 0; f < 2; f++) {
            int r = wm + f*16 + lr;
            af[f] = *(const bf16x8*)((const char*)As[buf] + r*64 + ((lh ^ (r & 3)) << 4));
        }
        #pragma unroll
        for (int f = 0; f < 4; f++) {
            int rn = wn + f*16 + lr;
            wf[f] = *(const bf16x8*)((const char*)Ws[buf] + rn*64 + ((lh ^ (rn & 3)) << 4));
        }
        #pragma unroll
        for (int fm = 0; fm < 2; fm++)
            #pragma unroll
            for (int fn = 0; fn < 4; fn++)
                acc[fm][fn] = __builtin_amdgcn_mfma_f32_16x16x32_bf16(af[fm], wf[fn], acc[fm][fn], 0, 0, 0);
    }

    #pragma unroll
    for (int fm = 0; fm < 2; fm++) {
        #pragma unroll
        for (int r = 0; r < 4; r++) {
            int row = bm + wm + fm*16 + lh*4 + r;
            #pragma unroll
            for (int fn = 0; fn < 4; fn++) {
                int col = bn + wn + fn*16 + lr;
                float v = acc[fm][fn][r];
                if (HASBIAS) v += bias[col];
                if (HASRES)  v += res[(size_t)row * N + col];
                if (OUTBF) ((u16*)outv)[(size_t)row * N + col] = f2bf(v);
                else       ((float*)outv)[(size_t)row * N + col] = v;
            }
        }
    }
}

// ---------------- QKV projection + Wc fold: 32x128 tiles, 3328 blocks XCD-chunked ----------------
// 416 panels of 32 A-rows (384 QKV + 32 Wc), 52 panels/XCD, 8 x-blocks each.
// 20KB LDS -> 8 blocks/CU (160KB, 2048 thr) = max TLP. z==2 (V) blocks write vt directly.
__global__ __launch_bounds__(256) void mqkv_k(const u16* __restrict__ qn,
                                              const u16* __restrict__ kn,
                                              const u16* __restrict__ wA,
                                              const float* __restrict__ bias3,
                                              u16* __restrict__ out3,
                                              const u16* __restrict__ wPb,
                                              const u16* __restrict__ wOt,
                                              u16* __restrict__ wCb,
                                              u16* __restrict__ vt) {
    __shared__ char smem[20480];
    char* AsB = smem;            // 2 bufs x 2048B (32x32 bf16)
    char* WsB = smem + 4096;     // 2 bufs x 8192B (128x32 bf16)

    int bid = blockIdx.x;
    int xcd = bid & 7, j = bid >> 3;
    int p = xcd * 52 + (j >> 3), x = j & 7;
    const u16* A; const u16* W; const float* bias = bias3; u16* out;
    int bm, bn = x * 128, hasb, isv = 0;
    if (p < 384) {
        int z = p >> 7, y = p & 127;
        A = z ? kn : qn; W = wA + (size_t)z * Cc * Cc;
        bias = bias3 + z * Cc; out = out3 + (size_t)z * Mm * Cc;
        bm = y * 32; hasb = 1; isv = (z == 2);
    } else {
        A = wPb; W = wOt; out = wCb;
        bm = (p - 384) * 32; hasb = 0;
    }

    int tid = threadIdx.x, w = tid >> 6, l = tid & 63;
    int lr = l & 15, lh = l >> 4;
    int wm = (w >> 1) * 16, wn = (w & 1) * 64;
    f32x4 acc[4] = {};

    auto stage = [&](int buf, int kt) {
        if (tid < 128) {
            int row = tid >> 2, slot = tid & 3;
            int ko = kt + ((slot ^ (row & 3)) << 3);
            gl16(A + (size_t)(bm + row) * Cc + ko, AsB + buf*2048 + tid * 16);
        }
        #pragma unroll
        for (int c = 0; c < 2; c++) {
            int i = c*256 + tid;
            int row = i >> 2, slot = i & 3;
            int ko = kt + ((slot ^ (row & 3)) << 3);
            gl16(W + (size_t)(bn + row) * Cc + ko, WsB + buf*8192 + (c*256 + tid) * 16);
        }
    };
    stage(0, 0);
    for (int kt = 0; kt < Cc; kt += 32) {
        int buf = (kt >> 5) & 1;
        __syncthreads();
        if (kt + 32 < Cc) stage(buf ^ 1, kt + 32);
        bf16x8 af, wf[4];
        {
            int r = wm + lr;
            af = *(const bf16x8*)(AsB + buf*2048 + r*64 + ((lh ^ (r & 3)) << 4));
        }
        #pragma unroll
        for (int f = 0; f < 4; f++) {
            int rn = wn + f*16 + lr;
            wf[f] = *(const bf16x8*)(WsB + buf*8192 + rn*64 + ((lh ^ (rn & 3)) << 4));
        }
        #pragma unroll
        for (int fn = 0; fn < 4; fn++)
            acc[fn] = __builtin_amdgcn_mfma_f32_16x16x32_bf16(af, wf[fn], acc[fn], 0, 0, 0);
    }

    if (!isv) {
        #pragma unroll
        for (int r = 0; r < 4; r++) {
            int orow = bm + wm + lh*4 + r;
            #pragma unroll
            for (int fn = 0; fn < 4; fn++) {
                int col = bn + wn + fn*16 + lr;
                float v = acc[fn][r];
                if (hasb) v += bias[col];
                out[(size_t)orow * Cc + col] = f2bf(v);
            }
        }
    } else {
        // transpose via LDS [32 t][130 pad] u16, then coalesced d-major writes to vt
        __syncthreads();               // all LDS reads of K-loop done
        u16* T = (u16*)smem;
        #pragma unroll
        for (int r = 0; r < 4; r++) {
            int lt = wm + lh*4 + r;
            #pragma unroll
            for (int fn = 0; fn < 4; fn++) {
                int c = wn + fn*16 + lr;
                T[lt*130 + c] = f2bf(acc[fn][r] + bias[bn + c]);
            }
        }
        __syncthreads();
        int b = bm >> 11, t0 = bm & 2047;
        int h0 = bn >> 6;
        #pragma unroll
        for (int i = 0; i < 16; i++) {
            int e = i*256 + tid;
            int dcol = e >> 5, t = e & 31;
            u16 v = T[t*130 + dcol];
            int h = h0 + (dcol >> 6), d = dcol & 63;
            vt[(size_t)((b*Hh + h)*HDi + d) * Tt + t0 + t] = v;
        }
    }
}

// ---------------- fused SwiGLU MFMA GEMM, 64x128 tile, dbuf ----------------
__global__ __launch_bounds__(256) void mswiglu64_k(const u16* __restrict__ A,
                                                   const u16* __restrict__ W1,
                                                   const u16* __restrict__ W2,
                                                   u16* __restrict__ out,
                                                   int N, int K) {
    __shared__ u16 As[2][64*32];
    __shared__ u16 W1s[2][128*32];
    __shared__ u16 W2s[2][128*32];
    int bm = blockIdx.y * 64, bn = blockIdx.x * 128;
    int tid = threadIdx.x, w = tid >> 6, l = tid & 63;
    int lr = l & 15, lh = l >> 4;
    int wm = (w >> 1) * 32, wn = (w & 1) * 64;
    f32x4 acc1[2][4] = {};
    f32x4 acc2[2][4] = {};

    auto stage = [&](int buf, int kt) {
        {
            int row = tid >> 2, slot = tid & 3;
            int ko = kt + ((slot ^ (row & 3)) << 3);
            gl16(A + (size_t)(bm + row) * K + ko, (char*)As[buf] + tid * 16);
        }
        #pragma unroll
        for (int c = 0; c < 2; c++) {
            int i = c*256 + tid;
            int row = i >> 2, slot = i & 3;
            int ko = kt + ((slot ^ (row & 3)) << 3);
            gl16(W1 + (size_t)(bn + row) * K + ko, (char*)W1s[buf] + (c*256 + tid) * 16);
            gl16(W2 + (size_t)(bn + row) * K + ko, (char*)W2s[buf] + (c*256 + tid) * 16);
        }
    };
    stage(0, 0);
    for (int kt = 0; kt < K; kt += 32) {
        int buf = (kt >> 5) & 1;
        __syncthreads();
        if (kt + 32 < K) stage(buf ^ 1, kt + 32);
        bf16x8 af[2], w1f[4], w2f[4];
        #pragma unroll
        for (int f = 0; f < 2; f++) {
            int r = wm + f*16 + lr;
            af[f] = *(const bf16x8*)((const char*)As[buf] + r*64 + ((lh ^ (r & 3)) << 4));
        }
        #pragma unroll
        for (int f = 0; f < 4; f++) {
            int rn = wn + f*16 + lr;
            int offn = rn*64 + ((lh ^ (rn & 3)) << 4);
            w1f[f] = *(const bf16x8*)((const char*)W1s[buf] + offn);
            w2f[f] = *(const bf16x8*)((const char*)W2s[buf] + offn);
        }
        #pragma unroll
        for (int fm = 0; fm < 2; fm++)
            #pragma unroll
            for (int fn = 0; fn < 4; fn++) {
                acc1[fm][fn] = __builtin_amdgcn_mfma_f32_16x16x32_bf16(af[fm], w1f[fn], acc1[fm][fn], 0, 0, 0);
                acc2[fm][fn] = __builtin_amdgcn_mfma_f32_16x16x32_bf16(af[fm], w2f[fn], acc2[fm][fn], 0, 0, 0);
            }
    }

    #pragma unroll
    for (int fm = 0; fm < 2; fm++) {
        #pragma unroll
        for (int r = 0; r < 4; r++) {
            int row = bm + wm + fm*16 + lh*4 + r;
            #pragma unroll
            for (int fn = 0; fn < 4; fn++) {
                int col = bn + wn + fn*16 + lr;
                float a = acc1[fm][fn][r];
                float sig = 1.f / (1.f + __expf(-a));
                out[(size_t)row * N + col] = f2bf(a * sig * acc2[fm][fn][r]);
            }
        }
    }
}

// ---------------- MFMA flash attention: KVBLK=128, lane-local P, FIXED-max softmax ----------------
__global__ __launch_bounds__(512) void fattn_k(const u16* __restrict__ qp,
                                               const u16* __restrict__ kp,
                                               const u16* __restrict__ vt,
                                               const float* __restrict__ mr,
                                               u16* __restrict__ ctx) {
    __shared__ alignas(128) u16 Kt[2*8192];   // dbuf 16KB tiles
    __shared__ alignas(128) u16 Vts[2*8192];
    __shared__ float mrw[2176];               // rel-bias window, pre-scaled by 8

    constexpr float C1  = 0.18033688011118324f;   // 0.125 * log2(e)
    constexpr float MNC = 64.f * C1;              // fixed max (v-domain) * C1

    int bid = blockIdx.x;
    int blk = ((bid & 7) << 6) | (bid >> 3);
    int qt = blk & 15, h = (blk >> 4) & 15, b = blk >> 8;
    int q0 = qt * 128;
    int tid = threadIdx.x, w = tid >> 6, l = tid & 63;
    int lr = l & 15, lh = l >> 4;
    size_t bc = (size_t)b * Tt * Cc + (size_t)h * HDi;
    const u16* vtb = vt + (size_t)(b*Hh + h) * HDi * Tt;

    for (int i = tid; i < 2175; i += 512) mrw[i] = mr[q0 + i] * 8.f;

    bf16x8 qa[2];
    {
        const u16* qrow = qp + bc + (size_t)(q0 + w*16 + lr) * Cc;
        qa[0] = *(const bf16x8*)(qrow + lh*8);
        qa[1] = *(const bf16x8*)(qrow + 32 + lh*8);
    }

    f32x4 oacc[4] = {};
    float lrun = 0.f;

    const char* pKb0 = (const char*)Kt + (lr>>2)*1024 + (lr&3)*128
                       + ((lh ^ (lr & 3)) << 4) + (((lr >> 2) & 1) << 6);
    const char* pKb1 = (const char*)((size_t)pKb0 ^ 64);
    int cr2 = lr >> 2;
    const char* pVb = (const char*)Vts + lr*256 + ((lh ^ (lr & 3)) << 4);
    const char* pVc0 = pVb + (((0 ^ cr2) & 3) << 6);
    const char* pVc1 = pVb + (((1 ^ cr2) & 3) << 6);
    const char* pVc2 = pVb + (((2 ^ cr2) & 3) << 6);
    const char* pVc3 = pVb + (((3 ^ cr2) & 3) << 6);
    const char* pm = (const char*)mrw + (w*16 + lr - lh*8 + 2047 - 103) * 4;

    int ksl = tid & 7, kr0 = tid >> 3;
    int so_k = (ksl ^ (kr0 & 7) ^ (((kr0 >> 3) & 1) << 2)) << 3;
    const u16* gK = kp + bc + (size_t)kr0 * Cc + so_k;
    int vsl = tid & 15, vr0 = tid >> 4;
    int so_v = (vsl ^ (vr0 & 15)) << 3;
    const u16* gV = vtb + (size_t)vr0 * Tt + so_v;
    int wb = (tid & 448) * 16;
    char* dK0 = (char*)Kt  + wb;
    char* dV0 = (char*)Vts + wb;

    auto stage = [&](int bufo) {
        gl16(gK,                      dK0 + bufo);
        gl16(gK + (size_t)64*Cc,      dK0 + bufo + 8192);
        gl16(gV,                      dV0 + bufo);
        gl16(gV + (size_t)32*Tt,      dV0 + bufo + 8192);
        gK += 128*Cc;
        gV += 128;
    };

    auto tile = [&](int bufo) {
        f32x4 s[8];
        #pragma unroll
        for (int f = 0; f < 8; f++) {
            int ob = 103 - (f & 1)*32 - ((f >> 1) & 1)*4 - (f >> 2)*64;
            s[f][0] = *(const float*)(pm + (ob    ) * 4);
            s[f][1] = *(const float*)(pm + (ob - 1) * 4);
            s[f][2] = *(const float*)(pm + (ob - 2) * 4);
            s[f][3] = *(const float*)(pm + (ob - 3) * 4);
        }
        pm -= 512;
        __builtin_amdgcn_s_setprio(1);
        {
            const char* k0 = pKb0 + bufo;
            const char* k1 = pKb1 + bufo;
            bf16x8 kb;
            kb = *(const bf16x8*)(k0 + 0);     s[0] = __builtin_amdgcn_mfma_f32_16x16x32_bf16(kb, qa[0], s[0], 0, 0, 0);
            kb = *(const bf16x8*)(k1 + 0);     s[0] = __builtin_amdgcn_mfma_f32_16x16x32_bf16(kb, qa[1], s[0], 0, 0, 0);
            kb = *(const bf16x8*)(k0 + 4096);  s[1] = __builtin_amdgcn_mfma_f32_16x16x32_bf16(kb, qa[0], s[1], 0, 0, 0);
            kb = *(const bf16x8*)(k1 + 4096);  s[1] = __builtin_amdgcn_mfma_f32_16x16x32_bf16(kb, qa[1], s[1], 0, 0, 0);
            kb = *(const bf16x8*)(k1 + 512);   s[2] = __builtin_amdgcn_mfma_f32_16x16x32_bf16(kb, qa[0], s[2], 0, 0, 0);
            kb = *(const bf16x8*)(k0 + 512);   s[2] = __builtin_amdgcn_mfma_f32_16x16x32_bf16(kb, qa[1], s[2], 0, 0, 0);
            kb = *(const bf16x8*)(k1 + 4608);  s[3] = __builtin_amdgcn_mfma_f32_16x16x32_bf16(kb, qa[0], s[3], 0, 0, 0);
            kb = *(const bf16x8*)(k0 + 4608);  s[3] = __builtin_amdgcn_mfma_f32_16x16x32_bf16(kb, qa[1], s[3], 0, 0, 0);
            kb = *(const bf16x8*)(k0 + 8192);  s[4] = __builtin_amdgcn_mfma_f32_16x16x32_bf16(kb, qa[0], s[4], 0, 0, 0);
            kb = *(const bf16x8*)(k1 + 8192);  s[4] = __builtin_amdgcn_mfma_f32_16x16x32_bf16(kb, qa[1], s[4], 0, 0, 0);
            kb = *(const bf16x8*)(k0 + 12288); s[5] = __builtin_amdgcn_mfma_f32_16x16x32_bf16(kb, qa[0], s[5], 0, 0, 0);
            kb = *(const bf16x8*)(k1 + 12288); s[5] = __builtin_amdgcn_mfma_f32_16x16x32_bf16(kb, qa[1], s[5], 0, 0, 0);
            kb = *(const bf16x8*)(k1 + 8704);  s[6] = __builtin_amdgcn_mfma_f32_16x16x32_bf16(kb, qa[0], s[6], 0, 0, 0);
            kb = *(const bf16x8*)(k0 + 8704);  s[6] = __builtin_amdgcn_mfma_f32_16x16x32_bf16(kb, qa[1], s[6], 0, 0, 0);
            kb = *(const bf16x8*)(k1 + 12800); s[7] = __builtin_amdgcn_mfma_f32_16x16x32_bf16(kb, qa[0], s[7], 0, 0, 0);
            kb = *(const bf16x8*)(k0 + 12800); s[7] = __builtin_amdgcn_mfma_f32_16x16x32_bf16(kb, qa[1], s[7], 0, 0, 0);
        }
        __builtin_amdgcn_s_setprio(0);

        // fixed-max softmax: exp starts immediately (no max tree / vote / rescale)
        float ts = 0.f;
        #pragma unroll
        for (int f = 0; f < 8; f++)
            #pragma unroll
            for (int r = 0; r < 4; r++) {
                float e = vexp2(fmaf(s[f][r], C1, -MNC));
                s[f][r] = e; ts += e;
            }
        ts += __shfl_xor(ts, 16);
        ts += __shfl_xor(ts, 32);
        lrun += ts;

        uint4 pb0u = { cvtpk(s[0][0], s[0][1]), cvtpk(s[0][2], s[0][3]),
                       cvtpk(s[2][0], s[2][1]), cvtpk(s[2][2], s[2][3]) };
        uint4 pb1u = { cvtpk(s[1][0], s[1][1]), cvtpk(s[1][2], s[1][3]),
                       cvtpk(s[3][0], s[3][1]), cvtpk(s[3][2], s[3][3]) };
        uint4 pb2u = { cvtpk(s[4][0], s[4][1]), cvtpk(s[4][2], s[4][3]),
                       cvtpk(s[6][0], s[6][1]), cvtpk(s[6][2], s[6][3]) };
        uint4 pb3u = { cvtpk(s[5][0], s[5][1]), cvtpk(s[5][2], s[5][3]),
                       cvtpk(s[7][0], s[7][1]), cvtpk(s[7][2], s[7][3]) };
        bf16x8 pb0 = __builtin_bit_cast(bf16x8, pb0u);
        bf16x8 pb1 = __builtin_bit_cast(bf16x8, pb1u);
        bf16x8 pb2 = __builtin_bit_cast(bf16x8, pb2u);
        bf16x8 pb3 = __builtin_bit_cast(bf16x8, pb3u);

        __builtin_amdgcn_s_setprio(1);
        #pragma unroll
        for (int ff = 0; ff < 4; ff++) {
            bf16x8 vb;
            vb = *(const bf16x8*)(pVc0 + bufo + ff*4096);
            oacc[ff] = __builtin_amdgcn_mfma_f32_16x16x32_bf16(vb, pb0, oacc[ff], 0, 0, 0);
            vb = *(const bf16x8*)(pVc1 + bufo + ff*4096);
            oacc[ff] = __builtin_amdgcn_mfma_f32_16x16x32_bf16(vb, pb1, oacc[ff], 0, 0, 0);
            vb = *(const bf16x8*)(pVc2 + bufo + ff*4096);
            oacc[ff] = __builtin_amdgcn_mfma_f32_16x16x32_bf16(vb, pb2, oacc[ff], 0, 0, 0);
            vb = *(const bf16x8*)(pVc3 + bufo + ff*4096);
            oacc[ff] = __builtin_amdgcn_mfma_f32_16x16x32_bf16(vb, pb3, oacc[ff], 0, 0, 0);
        }
        __builtin_amdgcn_s_setprio(0);
    };

    stage(0);
    #pragma unroll 1
    for (int kt = 0; kt < 16; kt += 2) {
        __syncthreads();
        stage(16384);
        tile(0);
        __syncthreads();
        if (kt < 14) stage(0);
        tile(16384);
    }

    float iv = 1.f / lrun;
    size_t rowoff = bc + (size_t)(q0 + w*16 + lr) * Cc;
    #pragma unroll
    for (int f = 0; f < 4; f++) {
        u16x4 o4 = { f2bf(oacc[f][0]*iv), f2bf(oacc[f][1]*iv),
                     f2bf(oacc[f][2]*iv), f2bf(oacc[f][3]*iv) };
        *(u16x4*)(ctx + rowoff + f*16 + lh*4) = o4;
    }
}

extern "C" void kernel_launch(void* const* d_in, const int* in_sizes, int n_in,
                              void* d_out, int out_size, void* d_ws, size_t ws_size,
                              hipStream_t stream) {
    const float* query     = (const float*)d_in[0];
    const float* key       = (const float*)d_in[1];
    const float* g_q       = (const float*)d_in[2];
    const float* b_q       = (const float*)d_in[3];
    const float* g_k       = (const float*)d_in[4];
    const float* b_k       = (const float*)d_in[5];
    const float* in_proj_w = (const float*)d_in[6];
    const float* in_proj_b = (const float*)d_in[7];
    const float* out_w     = (const float*)d_in[8];
    const float* out_b     = (const float*)d_in[9];
    const float* proj_w    = (const float*)d_in[10];
    const float* proj_b    = (const float*)d_in[11];
    const float* rel_table = (const float*)d_in[12];
    const float* g_ffn     = (const float*)d_in[13];
    const float* b_ffn     = (const float*)d_in[14];
    const float* w1        = (const float*)d_in[15];
    const float* w2        = (const float*)d_in[16];
    const float* w3        = (const float*)d_in[17];
    const float* g_out     = (const float*)d_in[18];
    const float* b_out     = (const float*)d_in[19];

    char* p = (char*)d_ws;
    auto alloc = [&](size_t bytes) { char* r = p; p += bytes; return r; };
    const size_t MCb = (size_t)Mm * Cc * 2;
    u16* wA  = (u16*)alloc((size_t)3*Cc*Cc*2);
    u16* wPb = (u16*)alloc((size_t)Cc*Cc*2);
    u16* wOt = (u16*)alloc((size_t)Cc*Cc*2);
    u16* wCb = (u16*)alloc((size_t)Cc*Cc*2);
    u16* w1b = (u16*)alloc((size_t)HIDP*Cc*2);
    u16* w2b = (u16*)alloc((size_t)HIDP*Cc*2);
    u16* w3b = (u16*)alloc((size_t)Cc*HIDP*2);
    float* bc = (float*)alloc(Cc*4);
    float* mr = (float*)alloc(4096*4);
    u16* qn = (u16*)alloc(MCb);
    u16* kn = (u16*)alloc(MCb);
    u16* qp = (u16*)alloc(MCb);      // qp,kp contiguous (mqkv out3; z=2 unused)
    u16* kp = (u16*)alloc(MCb);
    u16* vp = (u16*)alloc(MCb);      // region reserved (gf spans it)
    u16* vt = (u16*)alloc(MCb);
    float* x  = (float*)alloc((size_t)Mm*Cc*4);
    float* x2 = (float*)alloc((size_t)Mm*Cc*4);
    u16* ctx = qn;   // aliases (lifetimes disjoint)
    u16* h   = qp;
    u16* gf  = vp;   // [4096][1408] bf16 spans vp+part of vt (after fattn)

    dim3 blk(256);
    // merged prep + LN(q/k): 8192 LN blocks + 5456 prep blocks
    prepln_k<<<2*Mm + 5456, blk, 0, stream>>>(query, key, g_q, b_q, g_k, b_k, qn, kn,
                                              in_proj_w, wA, proj_w, wPb, w1, w1b, w2, w2b,
                                              w3, w3b, out_w, wOt, out_b, proj_b, bc, rel_table, mr);

    // QKV projections + Wc fold + V-transpose: 3328-block XCD-chunked grid (32-row tiles)
    mqkv_k<<<3328, blk, 0, stream>>>(qn, kn, wA, in_proj_b, qp, wPb, wOt, wCb, vt);

    fattn_k<<<Bb*Hh*16, dim3(512), 0, stream>>>(qp, kp, vt, mr, ctx);

    dim3 g1(Cc/128, Mm/64);
    mgemm64_k<0,1,1><<<g1, blk, 0, stream>>>(ctx, wCb, bc, query, x, Cc, Cc);

    ln_k<1><<<Mm, blk, 0, stream>>>(x, g_ffn, b_ffn, h);
    dim3 g2(HIDP/128, Mm/64);
    mswiglu64_k<<<g2, blk, 0, stream>>>(h, w1b, w2b, gf, HIDP, Cc);
    dim3 g3(Cc/128, Mm/64);
    mgemm64_k<0,1,0><<<g3, blk, 0, stream>>>(gf, w3b, nullptr, x, x2, Cc, HIDP);

    ln_k<0><<<Mm, blk, 0, stream>>>(x2, g_out, b_out, d_out);
}

// Round 24
// 229.770 us; speedup vs baseline: 1.0689x; 1.0689x over previous
//
#include <hip/hip_runtime.h>
#include <hip/hip_bf16.h>

static constexpr int Bb  = 2;
static constexpr int Tt  = 2048;
static constexpr int Cc  = 1024;
static constexpr int Hh  = 16;
static constexpr int HDi = 64;
static constexpr int HID = 1365;
static constexpr int HIDP = 1408;      // HID padded to multiple of 128
static constexpr int Mm  = Bb * Tt;    // 4096 rows

typedef unsigned short u16;
typedef __attribute__((ext_vector_type(8))) short bf16x8;
typedef __attribute__((ext_vector_type(4))) float f32x4;
typedef __attribute__((ext_vector_type(8))) unsigned short u16x8;
typedef __attribute__((ext_vector_type(4))) unsigned short u16x4;

__device__ inline u16 f2bf(float f) {
    unsigned u = __builtin_bit_cast(unsigned, f);
    u += 0x7fffu + ((u >> 16) & 1u);
    return (u16)(u >> 16);
}

__device__ inline unsigned cvtpk(float lo, float hi) {
    unsigned r;
    asm("v_cvt_pk_bf16_f32 %0, %1, %2" : "=v"(r) : "v"(lo), "v"(hi));
    return r;
}

__device__ inline float vexp2(float x) {   // raw v_exp_f32 (2^x)
    float r;
    asm("v_exp_f32 %0, %1" : "=v"(r) : "v"(x));
    return r;
}

__device__ inline void gl16(const void* g, void* l) {
    __builtin_amdgcn_global_load_lds(
        (const __attribute__((address_space(1))) unsigned*)g,
        (__attribute__((address_space(3))) unsigned*)l, 16, 0, 0);
}

// ---------------- LayerNorm: one row (C=1024) per block; OUTBF: bf16 out ----------------
template<int OUTBF>
__global__ __launch_bounds__(256) void ln_k(const float* __restrict__ x,
                                            const float* __restrict__ g,
                                            const float* __restrict__ b,
                                            void* __restrict__ yv) {
    int row = blockIdx.x;
    int tid = threadIdx.x;
    const float4* xr = (const float4*)(x + (size_t)row * Cc);
    float4 v = xr[tid];
    float s  = v.x + v.y + v.z + v.w;
    float ss = v.x*v.x + v.y*v.y + v.z*v.z + v.w*v.w;
    __shared__ float rs[256], rq[256];
    rs[tid] = s; rq[tid] = ss;
    __syncthreads();
    for (int o = 128; o > 0; o >>= 1) {
        if (tid < o) { rs[tid] += rs[tid+o]; rq[tid] += rq[tid+o]; }
        __syncthreads();
    }
    float mean = rs[0] * (1.f/Cc);
    float var  = rq[0] * (1.f/Cc) - mean*mean;
    float inv  = rsqrtf(var + 1e-5f);
    float4 gv = ((const float4*)g)[tid];
    float4 bv = ((const float4*)b)[tid];
    float o0 = (v.x-mean)*inv*gv.x + bv.x;
    float o1 = (v.y-mean)*inv*gv.y + bv.y;
    float o2 = (v.z-mean)*inv*gv.z + bv.z;
    float o3 = (v.w-mean)*inv*gv.w + bv.w;
    if (OUTBF) {
        u16x4 o4 = { f2bf(o0), f2bf(o1), f2bf(o2), f2bf(o3) };
        ((u16x4*)((u16*)yv + (size_t)row * Cc))[tid] = o4;
    } else {
        float4 o4 = { o0, o1, o2, o3 };
        ((float4*)((float*)yv + (size_t)row * Cc))[tid] = o4;
    }
}

// ---------------- merged prep + LN(query)+LN(key) ----------------
__global__ __launch_bounds__(256) void prepln_k(const float* __restrict__ query,
                                                const float* __restrict__ key,
                                                const float* __restrict__ gq, const float* __restrict__ bq,
                                                const float* __restrict__ gk, const float* __restrict__ bk,
                                                u16* __restrict__ qn, u16* __restrict__ kn,
                                                const float* __restrict__ in_proj_w, u16* __restrict__ wA,
                                                const float* __restrict__ proj_w,  u16* __restrict__ wPb,
                                                const float* __restrict__ w1, u16* __restrict__ w1b,
                                                const float* __restrict__ w2, u16* __restrict__ w2b,
                                                const float* __restrict__ w3, u16* __restrict__ w3b,
                                                const float* __restrict__ out_w, u16* __restrict__ wOt,
                                                const float* __restrict__ out_b, const float* __restrict__ bp,
                                                float* __restrict__ bc,
                                                const float* __restrict__ rel, float* __restrict__ mr) {
    __shared__ float sh[64*65];
    int bid = blockIdx.x, tid = threadIdx.x;
    if (bid < 2*Mm) {
        const float* x; const float* g; const float* bb; u16* y; int r;
        if (bid < Mm) { x = query; g = gq; bb = bq; y = qn; r = bid; }
        else          { x = key;   g = gk; bb = bk; y = kn; r = bid - Mm; }
        float4 v = ((const float4*)(x + (size_t)r * Cc))[tid];
        float s  = v.x + v.y + v.z + v.w;
        float ss = v.x*v.x + v.y*v.y + v.z*v.z + v.w*v.w;
        float* rs = sh; float* rq2 = sh + 256;
        rs[tid] = s; rq2[tid] = ss;
        __syncthreads();
        for (int o = 128; o > 0; o >>= 1) {
            if (tid < o) { rs[tid] += rs[tid+o]; rq2[tid] += rq2[tid+o]; }
            __syncthreads();
        }
        float mean = rs[0] * (1.f/Cc);
        float var  = rq2[0] * (1.f/Cc) - mean*mean;
        float inv  = rsqrtf(var + 1e-5f);
        float4 gv = ((const float4*)g)[tid];
        float4 bv = ((const float4*)bb)[tid];
        u16x4 o4 = { f2bf((v.x-mean)*inv*gv.x + bv.x), f2bf((v.y-mean)*inv*gv.y + bv.y),
                     f2bf((v.z-mean)*inv*gv.z + bv.z), f2bf((v.w-mean)*inv*gv.w + bv.w) };
        ((u16x4*)(y + (size_t)r * Cc))[tid] = o4;
        return;
    }
    bid -= 2*Mm;
    if (bid < 3456) {
        int u = bid * 256 + tid;
        const float* src; u16* dst; int valid;
        if (u < 1536*256)                   { src = in_proj_w; dst = wA;  valid = 3*Cc*Cc; }
        else if ((u -= 1536*256) < 512*256) { src = proj_w;    dst = wPb; valid = Cc*Cc; }
        else if ((u -= 512*256) < 704*256)  { src = w1;        dst = w1b; valid = HID*Cc; }
        else     { u -= 704*256;              src = w2;        dst = w2b; valid = HID*Cc; }
        int e0 = u * 8;
        u16x8 o;
        if (e0 + 8 <= valid) {
            float4 a = *(const float4*)(src + e0);
            float4 b = *(const float4*)(src + e0 + 4);
            o[0]=f2bf(a.x); o[1]=f2bf(a.y); o[2]=f2bf(a.z); o[3]=f2bf(a.w);
            o[4]=f2bf(b.x); o[5]=f2bf(b.y); o[6]=f2bf(b.z); o[7]=f2bf(b.w);
        } else {
            #pragma unroll
            for (int j = 0; j < 8; j++) { int e = e0 + j; o[j] = f2bf(e < valid ? src[e] : 0.f); }
        }
        *(u16x8*)(dst + (size_t)e0) = o;
    } else if (bid < 4160) {
        int idx = (bid - 3456) * 256 + tid;
        int e0 = idx * 8;
        int r = e0 / HIDP, c0 = e0 - r * HIDP;
        u16x8 o;
        #pragma unroll
        for (int j = 0; j < 8; j++) {
            int c = c0 + j;
            o[j] = f2bf(c < HID ? w3[(size_t)r * HID + c] : 0.f);
        }
        *(u16x8*)(w3b + (size_t)e0) = o;
    } else if (bid < 4416) {
        int id = bid - 4160;
        int j0 = (id & 15) * 64, c0 = (id >> 4) * 64;
        #pragma unroll
        for (int i = 0; i < 16; i++) {
            int e = tid + i*256;
            int c = e >> 6, j = e & 63;
            sh[c*65 + j] = out_w[(size_t)(c0 + c) * Cc + j0 + j];
        }
        __syncthreads();
        #pragma unroll
        for (int i = 0; i < 16; i++) {
            int e = tid + i*256;
            int j = e >> 6, c = e & 63;
            wOt[(size_t)(j0 + j) * Cc + c0 + c] = f2bf(sh[c*65 + j]);
        }
    } else if (bid < 5440) {
        int i = bid - 4416;
        float4 w = ((const float4*)(proj_w + (size_t)i * Cc))[tid];
        float4 b = ((const float4*)out_b)[tid];
        float s = w.x*b.x + w.y*b.y + w.z*b.z + w.w*b.w;
        sh[tid] = s; __syncthreads();
        for (int o = 128; o > 0; o >>= 1) {
            if (tid < o) sh[tid] += sh[tid+o];
            __syncthreads();
        }
        if (tid == 0) bc[i] = sh[0] + bp[i];
    } else {
        int j = (bid - 5440) * 256 + tid;
        if (j < 2*Tt - 1) {
            float s = 0.f;
            #pragma unroll
            for (int h = 0; h < Hh; h++) s += rel[(size_t)h * (2*Tt - 1) + j];
            mr[j] = s * (1.f/Hh);
        }
    }
}

// ---------------- bf16 MFMA GEMM 64x128 tile, dbuf + 1 barrier/K-step ----------------
template<int OUTBF, int HASRES, int HASBIAS>
__global__ __launch_bounds__(256) void mgemm64_k(const u16* __restrict__ A,
                                                 const u16* __restrict__ W,
                                                 const float* __restrict__ bias,
                                                 const float* __restrict__ res,
                                                 void* __restrict__ outv,
                                                 int N, int K) {
    __shared__ u16 As[2][64*32];
    __shared__ u16 Ws[2][128*32];
    int bm = blockIdx.y * 64, bn = blockIdx.x * 128;
    int tid = threadIdx.x, w = tid >> 6, l = tid & 63;
    int lr = l & 15, lh = l >> 4;
    int wm = (w >> 1) * 32, wn = (w & 1) * 64;
    f32x4 acc[2][4] = {};

    auto stage = [&](int buf, int kt) {
        {
            int row = tid >> 2, slot = tid & 3;
            int ko = kt + ((slot ^ (row & 3)) << 3);
            gl16(A + (size_t)(bm + row) * K + ko, (char*)As[buf] + tid * 16);
        }
        #pragma unroll
        for (int c = 0; c < 2; c++) {
            int i = c*256 + tid;
            int row = i >> 2, slot = i & 3;
            int ko = kt + ((slot ^ (row & 3)) << 3);
            gl16(W + (size_t)(bn + row) * K + ko, (char*)Ws[buf] + (c*256 + tid) * 16);
        }
    };
    stage(0, 0);
    for (int kt = 0; kt < K; kt += 32) {
        int buf = (kt >> 5) & 1;
        __syncthreads();
        if (kt + 32 < K) stage(buf ^ 1, kt + 32);
        bf16x8 af[2], wf[4];
        #pragma unroll
        for (int f = 0; f < 2; f++) {
            int r = wm + f*16 + lr;
            af[f] = *(const bf16x8*)((const char*)As[buf] + r*64 + ((lh ^ (r & 3)) << 4));
        }
        #pragma unroll
        for (int f = 0; f < 4; f++) {
            int rn = wn + f*16 + lr;
            wf[f] = *(const bf16x8*)((const char*)Ws[buf] + rn*64 + ((lh ^ (rn & 3)) << 4));
        }
        #pragma unroll
        for (int fm = 0; fm < 2; fm++)
            #pragma unroll
            for (int fn = 0; fn < 4; fn++)
                acc[fm][fn] = __builtin_amdgcn_mfma_f32_16x16x32_bf16(af[fm], wf[fn], acc[fm][fn], 0, 0, 0);
    }

    #pragma unroll
    for (int fm = 0; fm < 2; fm++) {
        #pragma unroll
        for (int r = 0; r < 4; r++) {
            int row = bm + wm + fm*16 + lh*4 + r;
            #pragma unroll
            for (int fn = 0; fn < 4; fn++) {
                int col = bn + wn + fn*16 + lr;
                float v = acc[fm][fn][r];
                if (HASBIAS) v += bias[col];
                if (HASRES)  v += res[(size_t)row * N + col];
                if (OUTBF) ((u16*)outv)[(size_t)row * N + col] = f2bf(v);
                else       ((float*)outv)[(size_t)row * N + col] = v;
            }
        }
    }
}

// ---------------- QKV projection + Wc fold: 64x128 tiles, 1664 blocks XCD-chunked ----------------
// z==2 (V) blocks transpose in-LDS and write vt[B*H,64,T] directly (vt_k folded in).
__global__ __launch_bounds__(256) void mqkv_k(const u16* __restrict__ qn,
                                              const u16* __restrict__ kn,
                                              const u16* __restrict__ wA,
                                              const float* __restrict__ bias3,
                                              u16* __restrict__ out3,
                                              const u16* __restrict__ wPb,
                                              const u16* __restrict__ wOt,
                                              u16* __restrict__ wCb,
                                              u16* __restrict__ vt) {
    __shared__ char smem[24576];
    char* AsB = smem;            // 2 bufs x 4096B (64x32 bf16)
    char* WsB = smem + 8192;     // 2 bufs x 8192B (128x32 bf16)

    int bid = blockIdx.x;
    int xcd = bid & 7, j = bid >> 3;
    int p = xcd * 26 + (j >> 3), x = j & 7;
    const u16* A; const u16* W; const float* bias = bias3; u16* out;
    int bm, bn = x * 128, hasb, isv = 0;
    if (p < 192) {
        int z = p >> 6, y = p & 63;
        A = z ? kn : qn; W = wA + (size_t)z * Cc * Cc;
        bias = bias3 + z * Cc; out = out3 + (size_t)z * Mm * Cc;
        bm = y * 64; hasb = 1; isv = (z == 2);
    } else {
        A = wPb; W = wOt; out = wCb;
        bm = (p - 192) * 64; hasb = 0;
    }

    int tid = threadIdx.x, w = tid >> 6, l = tid & 63;
    int lr = l & 15, lh = l >> 4;
    int wm = (w >> 1) * 32, wn = (w & 1) * 64;
    f32x4 acc[2][4] = {};

    auto stage = [&](int buf, int kt) {
        {
            int row = tid >> 2, slot = tid & 3;
            int ko = kt + ((slot ^ (row & 3)) << 3);
            gl16(A + (size_t)(bm + row) * Cc + ko, AsB + buf*4096 + tid * 16);
        }
        #pragma unroll
        for (int c = 0; c < 2; c++) {
            int i = c*256 + tid;
            int row = i >> 2, slot = i & 3;
            int ko = kt + ((slot ^ (row & 3)) << 3);
            gl16(W + (size_t)(bn + row) * Cc + ko, WsB + buf*8192 + (c*256 + tid) * 16);
        }
    };
    stage(0, 0);
    for (int kt = 0; kt < Cc; kt += 32) {
        int buf = (kt >> 5) & 1;
        __syncthreads();
        if (kt + 32 < Cc) stage(buf ^ 1, kt + 32);
        bf16x8 af[2], wf[4];
        #pragma unroll
        for (int f = 0; f < 2; f++) {
            int r = wm + f*16 + lr;
            af[f] = *(const bf16x8*)(AsB + buf*4096 + r*64 + ((lh ^ (r & 3)) << 4));
        }
        #pragma unroll
        for (int f = 0; f < 4; f++) {
            int rn = wn + f*16 + lr;
            wf[f] = *(const bf16x8*)(WsB + buf*8192 + rn*64 + ((lh ^ (rn & 3)) << 4));
        }
        #pragma unroll
        for (int fm = 0; fm < 2; fm++)
            #pragma unroll
            for (int fn = 0; fn < 4; fn++)
                acc[fm][fn] = __builtin_amdgcn_mfma_f32_16x16x32_bf16(af[fm], wf[fn], acc[fm][fn], 0, 0, 0);
    }

    if (!isv) {
        #pragma unroll
        for (int fm = 0; fm < 2; fm++) {
            #pragma unroll
            for (int r = 0; r < 4; r++) {
                int orow = bm + wm + fm*16 + lh*4 + r;
                #pragma unroll
                for (int fn = 0; fn < 4; fn++) {
                    int col = bn + wn + fn*16 + lr;
                    float v = acc[fm][fn][r];
                    if (hasb) v += bias[col];
                    out[(size_t)orow * Cc + col] = f2bf(v);
                }
            }
        }
    } else {
        // transpose via LDS [64 t][130 pad] u16, then coalesced d-major writes to vt
        __syncthreads();               // all LDS reads of K-loop done
        u16* T = (u16*)smem;
        #pragma unroll
        for (int fm = 0; fm < 2; fm++)
            #pragma unroll
            for (int r = 0; r < 4; r++) {
                int lt = wm + fm*16 + lh*4 + r;
                #pragma unroll
                for (int fn = 0; fn < 4; fn++) {
                    int c = wn + fn*16 + lr;
                    T[lt*130 + c] = f2bf(acc[fm][fn][r] + bias[bn + c]);
                }
            }
        __syncthreads();
        int b = bm >> 11, t0 = bm & 2047;
        int h0 = bn >> 6;
        #pragma unroll
        for (int i = 0; i < 32; i++) {
            int e = i*256 + tid;
            int dcol = e >> 6, t = e & 63;
            u16 v = T[t*130 + dcol];
            int h = h0 + (dcol >> 6), d = dcol & 63;
            vt[(size_t)((b*Hh + h)*HDi + d) * Tt + t0 + t] = v;
        }
    }
}

// ---------------- fused SwiGLU MFMA GEMM, 64x128 tile, dbuf ----------------
__global__ __launch_bounds__(256) void mswiglu64_k(const u16* __restrict__ A,
                                                   const u16* __restrict__ W1,
                                                   const u16* __restrict__ W2,
                                                   u16* __restrict__ out,
                                                   int N, int K) {
    __shared__ u16 As[2][64*32];
    __shared__ u16 W1s[2][128*32];
    __shared__ u16 W2s[2][128*32];
    int bm = blockIdx.y * 64, bn = blockIdx.x * 128;
    int tid = threadIdx.x, w = tid >> 6, l = tid & 63;
    int lr = l & 15, lh = l >> 4;
    int wm = (w >> 1) * 32, wn = (w & 1) * 64;
    f32x4 acc1[2][4] = {};
    f32x4 acc2[2][4] = {};

    auto stage = [&](int buf, int kt) {
        {
            int row = tid >> 2, slot = tid & 3;
            int ko = kt + ((slot ^ (row & 3)) << 3);
            gl16(A + (size_t)(bm + row) * K + ko, (char*)As[buf] + tid * 16);
        }
        #pragma unroll
        for (int c = 0; c < 2; c++) {
            int i = c*256 + tid;
            int row = i >> 2, slot = i & 3;
            int ko = kt + ((slot ^ (row & 3)) << 3);
            gl16(W1 + (size_t)(bn + row) * K + ko, (char*)W1s[buf] + (c*256 + tid) * 16);
            gl16(W2 + (size_t)(bn + row) * K + ko, (char*)W2s[buf] + (c*256 + tid) * 16);
        }
    };
    stage(0, 0);
    for (int kt = 0; kt < K; kt += 32) {
        int buf = (kt >> 5) & 1;
        __syncthreads();
        if (kt + 32 < K) stage(buf ^ 1, kt + 32);
        bf16x8 af[2], w1f[4], w2f[4];
        #pragma unroll
        for (int f = 0; f < 2; f++) {
            int r = wm + f*16 + lr;
            af[f] = *(const bf16x8*)((const char*)As[buf] + r*64 + ((lh ^ (r & 3)) << 4));
        }
        #pragma unroll
        for (int f = 0; f < 4; f++) {
            int rn = wn + f*16 + lr;
            int offn = rn*64 + ((lh ^ (rn & 3)) << 4);
            w1f[f] = *(const bf16x8*)((const char*)W1s[buf] + offn);
            w2f[f] = *(const bf16x8*)((const char*)W2s[buf] + offn);
        }
        #pragma unroll
        for (int fm = 0; fm < 2; fm++)
            #pragma unroll
            for (int fn = 0; fn < 4; fn++) {
                acc1[fm][fn] = __builtin_amdgcn_mfma_f32_16x16x32_bf16(af[fm], w1f[fn], acc1[fm][fn], 0, 0, 0);
                acc2[fm][fn] = __builtin_amdgcn_mfma_f32_16x16x32_bf16(af[fm], w2f[fn], acc2[fm][fn], 0, 0, 0);
            }
    }

    #pragma unroll
    for (int fm = 0; fm < 2; fm++) {
        #pragma unroll
        for (int r = 0; r < 4; r++) {
            int row = bm + wm + fm*16 + lh*4 + r;
            #pragma unroll
            for (int fn = 0; fn < 4; fn++) {
                int col = bn + wn + fn*16 + lr;
                float a = acc1[fm][fn][r];
                float sig = 1.f / (1.f + __expf(-a));
                out[(size_t)row * N + col] = f2bf(a * sig * acc2[fm][fn][r]);
            }
        }
    }
}

// ---------------- MFMA flash attention: KVBLK=128, lane-local P, FIXED-max softmax ----------------
__global__ __launch_bounds__(512) void fattn_k(const u16* __restrict__ qp,
                                               const u16* __restrict__ kp,
                                               const u16* __restrict__ vt,
                                               const float* __restrict__ mr,
                                               u16* __restrict__ ctx) {
    __shared__ alignas(128) u16 Kt[2*8192];   // dbuf 16KB tiles
    __shared__ alignas(128) u16 Vts[2*8192];
    __shared__ float mrw[2176];               // rel-bias window, pre-scaled by 8

    constexpr float C1  = 0.18033688011118324f;   // 0.125 * log2(e)
    constexpr float MNC = 64.f * C1;              // fixed max (v-domain) * C1

    int bid = blockIdx.x;
    int blk = ((bid & 7) << 6) | (bid >> 3);
    int qt = blk & 15, h = (blk >> 4) & 15, b = blk >> 8;
    int q0 = qt * 128;
    int tid = threadIdx.x, w = tid >> 6, l = tid & 63;
    int lr = l & 15, lh = l >> 4;
    size_t bc = (size_t)b * Tt * Cc + (size_t)h * HDi;
    const u16* vtb = vt + (size_t)(b*Hh + h) * HDi * Tt;

    for (int i = tid; i < 2175; i += 512) mrw[i] = mr[q0 + i] * 8.f;

    bf16x8 qa[2];
    {
        const u16* qrow = qp + bc + (size_t)(q0 + w*16 + lr) * Cc;
        qa[0] = *(const bf16x8*)(qrow + lh*8);
        qa[1] = *(const bf16x8*)(qrow + 32 + lh*8);
    }

    f32x4 oacc[4] = {};
    float lrun = 0.f;

    const char* pKb0 = (const char*)Kt + (lr>>2)*1024 + (lr&3)*128
                       + ((lh ^ (lr & 3)) << 4) + (((lr >> 2) & 1) << 6);
    const char* pKb1 = (const char*)((size_t)pKb0 ^ 64);
    int cr2 = lr >> 2;
    const char* pVb = (const char*)Vts + lr*256 + ((lh ^ (lr & 3)) << 4);
    const char* pVc0 = pVb + (((0 ^ cr2) & 3) << 6);
    const char* pVc1 = pVb + (((1 ^ cr2) & 3) << 6);
    const char* pVc2 = pVb + (((2 ^ cr2) & 3) << 6);
    const char* pVc3 = pVb + (((3 ^ cr2) & 3) << 6);
    const char* pm = (const char*)mrw + (w*16 + lr - lh*8 + 2047 - 103) * 4;

    int ksl = tid & 7, kr0 = tid >> 3;
    int so_k = (ksl ^ (kr0 & 7) ^ (((kr0 >> 3) & 1) << 2)) << 3;
    const u16* gK = kp + bc + (size_t)kr0 * Cc + so_k;
    int vsl = tid & 15, vr0 = tid >> 4;
    int so_v = (vsl ^ (vr0 & 15)) << 3;
    const u16* gV = vtb + (size_t)vr0 * Tt + so_v;
    int wb = (tid & 448) * 16;
    char* dK0 = (char*)Kt  + wb;
    char* dV0 = (char*)Vts + wb;

    auto stage = [&](int bufo) {
        gl16(gK,                      dK0 + bufo);
        gl16(gK + (size_t)64*Cc,      dK0 + bufo + 8192);
        gl16(gV,                      dV0 + bufo);
        gl16(gV + (size_t)32*Tt,      dV0 + bufo + 8192);
        gK += 128*Cc;
        gV += 128;
    };

    auto tile = [&](int bufo) {
        f32x4 s[8];
        #pragma unroll
        for (int f = 0; f < 8; f++) {
            int ob = 103 - (f & 1)*32 - ((f >> 1) & 1)*4 - (f >> 2)*64;
            s[f][0] = *(const float*)(pm + (ob    ) * 4);
            s[f][1] = *(const float*)(pm + (ob - 1) * 4);
            s[f][2] = *(const float*)(pm + (ob - 2) * 4);
            s[f][3] = *(const float*)(pm + (ob - 3) * 4);
        }
        pm -= 512;
        __builtin_amdgcn_s_setprio(1);
        {
            const char* k0 = pKb0 + bufo;
            const char* k1 = pKb1 + bufo;
            bf16x8 kb;
            kb = *(const bf16x8*)(k0 + 0);     s[0] = __builtin_amdgcn_mfma_f32_16x16x32_bf16(kb, qa[0], s[0], 0, 0, 0);
            kb = *(const bf16x8*)(k1 + 0);     s[0] = __builtin_amdgcn_mfma_f32_16x16x32_bf16(kb, qa[1], s[0], 0, 0, 0);
            kb = *(const bf16x8*)(k0 + 4096);  s[1] = __builtin_amdgcn_mfma_f32_16x16x32_bf16(kb, qa[0], s[1], 0, 0, 0);
            kb = *(const bf16x8*)(k1 + 4096);  s[1] = __builtin_amdgcn_mfma_f32_16x16x32_bf16(kb, qa[1], s[1], 0, 0, 0);
            kb = *(const bf16x8*)(k1 + 512);   s[2] = __builtin_amdgcn_mfma_f32_16x16x32_bf16(kb, qa[0], s[2], 0, 0, 0);
            kb = *(const bf16x8*)(k0 + 512);   s[2] = __builtin_amdgcn_mfma_f32_16x16x32_bf16(kb, qa[1], s[2], 0, 0, 0);
            kb = *(const bf16x8*)(k1 + 4608);  s[3] = __builtin_amdgcn_mfma_f32_16x16x32_bf16(kb, qa[0], s[3], 0, 0, 0);
            kb = *(const bf16x8*)(k0 + 4608);  s[3] = __builtin_amdgcn_mfma_f32_16x16x32_bf16(kb, qa[1], s[3], 0, 0, 0);
            kb = *(const bf16x8*)(k0 + 8192);  s[4] = __builtin_amdgcn_mfma_f32_16x16x32_bf16(kb, qa[0], s[4], 0, 0, 0);
            kb = *(const bf16x8*)(k1 + 8192);  s[4] = __builtin_amdgcn_mfma_f32_16x16x32_bf16(kb, qa[1], s[4], 0, 0, 0);
            kb = *(const bf16x8*)(k0 + 12288); s[5] = __builtin_amdgcn_mfma_f32_16x16x32_bf16(kb, qa[0], s[5], 0, 0, 0);
            kb = *(const bf16x8*)(k1 + 12288); s[5] = __builtin_amdgcn_mfma_f32_16x16x32_bf16(kb, qa[1], s[5], 0, 0, 0);
            kb = *(const bf16x8*)(k1 + 8704);  s[6] = __builtin_amdgcn_mfma_f32_16x16x32_bf16(kb, qa[0], s[6], 0, 0, 0);
            kb = *(const bf16x8*)(k0 + 8704);  s[6] = __builtin_amdgcn_mfma_f32_16x16x32_bf16(kb, qa[1], s[6], 0, 0, 0);
            kb = *(const bf16x8*)(k1 + 12800); s[7] = __builtin_amdgcn_mfma_f32_16x16x32_bf16(kb, qa[0], s[7], 0, 0, 0);
            kb = *(const bf16x8*)(k0 + 12800); s[7] = __builtin_amdgcn_mfma_f32_16x16x32_bf16(kb, qa[1], s[7], 0, 0, 0);
        }
        __builtin_amdgcn_s_setprio(0);

        // fixed-max softmax: exp starts immediately (no max tree / vote / rescale)
        float ts = 0.f;
        #pragma unroll
        for (int f = 0; f < 8; f++)
            #pragma unroll
            for (int r = 0; r < 4; r++) {
                float e = vexp2(fmaf(s[f][r], C1, -MNC));
                s[f][r] = e; ts += e;
            }
        ts += __shfl_xor(ts, 16);
        ts += __shfl_xor(ts, 32);
        lrun += ts;

        uint4 pb0u = { cvtpk(s[0][0], s[0][1]), cvtpk(s[0][2], s[0][3]),
                       cvtpk(s[2][0], s[2][1]), cvtpk(s[2][2], s[2][3]) };
        uint4 pb1u = { cvtpk(s[1][0], s[1][1]), cvtpk(s[1][2], s[1][3]),
                       cvtpk(s[3][0], s[3][1]), cvtpk(s[3][2], s[3][3]) };
        uint4 pb2u = { cvtpk(s[4][0], s[4][1]), cvtpk(s[4][2], s[4][3]),
                       cvtpk(s[6][0], s[6][1]), cvtpk(s[6][2], s[6][3]) };
        uint4 pb3u = { cvtpk(s[5][0], s[5][1]), cvtpk(s[5][2], s[5][3]),
                       cvtpk(s[7][0], s[7][1]), cvtpk(s[7][2], s[7][3]) };
        bf16x8 pb0 = __builtin_bit_cast(bf16x8, pb0u);
        bf16x8 pb1 = __builtin_bit_cast(bf16x8, pb1u);
        bf16x8 pb2 = __builtin_bit_cast(bf16x8, pb2u);
        bf16x8 pb3 = __builtin_bit_cast(bf16x8, pb3u);

        __builtin_amdgcn_s_setprio(1);
        #pragma unroll
        for (int ff = 0; ff < 4; ff++) {
            bf16x8 vb;
            vb = *(const bf16x8*)(pVc0 + bufo + ff*4096);
            oacc[ff] = __builtin_amdgcn_mfma_f32_16x16x32_bf16(vb, pb0, oacc[ff], 0, 0, 0);
            vb = *(const bf16x8*)(pVc1 + bufo + ff*4096);
            oacc[ff] = __builtin_amdgcn_mfma_f32_16x16x32_bf16(vb, pb1, oacc[ff], 0, 0, 0);
            vb = *(const bf16x8*)(pVc2 + bufo + ff*4096);
            oacc[ff] = __builtin_amdgcn_mfma_f32_16x16x32_bf16(vb, pb2, oacc[ff], 0, 0, 0);
            vb = *(const bf16x8*)(pVc3 + bufo + ff*4096);
            oacc[ff] = __builtin_amdgcn_mfma_f32_16x16x32_bf16(vb, pb3, oacc[ff], 0, 0, 0);
        }
        __builtin_amdgcn_s_setprio(0);
    };

    stage(0);
    #pragma unroll 1
    for (int kt = 0; kt < 16; kt += 2) {
        __syncthreads();
        stage(16384);
        tile(0);
        __syncthreads();
        if (kt < 14) stage(0);
        tile(16384);
    }

    float iv = 1.f / lrun;
    size_t rowoff = bc + (size_t)(q0 + w*16 + lr) * Cc;
    #pragma unroll
    for (int f = 0; f < 4; f++) {
        u16x4 o4 = { f2bf(oacc[f][0]*iv), f2bf(oacc[f][1]*iv),
                     f2bf(oacc[f][2]*iv), f2bf(oacc[f][3]*iv) };
        *(u16x4*)(ctx + rowoff + f*16 + lh*4) = o4;
    }
}

extern "C" void kernel_launch(void* const* d_in, const int* in_sizes, int n_in,
                              void* d_out, int out_size, void* d_ws, size_t ws_size,
                              hipStream_t stream) {
    const float* query     = (const float*)d_in[0];
    const float* key       = (const float*)d_in[1];
    const float* g_q       = (const float*)d_in[2];
    const float* b_q       = (const float*)d_in[3];
    const float* g_k       = (const float*)d_in[4];
    const float* b_k       = (const float*)d_in[5];
    const float* in_proj_w = (const float*)d_in[6];
    const float* in_proj_b = (const float*)d_in[7];
    const float* out_w     = (const float*)d_in[8];
    const float* out_b     = (const float*)d_in[9];
    const float* proj_w    = (const float*)d_in[10];
    const float* proj_b    = (const float*)d_in[11];
    const float* rel_table = (const float*)d_in[12];
    const float* g_ffn     = (const float*)d_in[13];
    const float* b_ffn     = (const float*)d_in[14];
    const float* w1        = (const float*)d_in[15];
    const float* w2        = (const float*)d_in[16];
    const float* w3        = (const float*)d_in[17];
    const float* g_out     = (const float*)d_in[18];
    const float* b_out     = (const float*)d_in[19];

    char* p = (char*)d_ws;
    auto alloc = [&](size_t bytes) { char* r = p; p += bytes; return r; };
    const size_t MCb = (size_t)Mm * Cc * 2;
    u16* wA  = (u16*)alloc((size_t)3*Cc*Cc*2);
    u16* wPb = (u16*)alloc((size_t)Cc*Cc*2);
    u16* wOt = (u16*)alloc((size_t)Cc*Cc*2);
    u16* wCb = (u16*)alloc((size_t)Cc*Cc*2);
    u16* w1b = (u16*)alloc((size_t)HIDP*Cc*2);
    u16* w2b = (u16*)alloc((size_t)HIDP*Cc*2);
    u16* w3b = (u16*)alloc((size_t)Cc*HIDP*2);
    float* bc = (float*)alloc(Cc*4);
    float* mr = (float*)alloc(4096*4);
    u16* qn = (u16*)alloc(MCb);
    u16* kn = (u16*)alloc(MCb);
    u16* qp = (u16*)alloc(MCb);      // qp,kp contiguous (mqkv out3; z=2 unused)
    u16* kp = (u16*)alloc(MCb);
    u16* vp = (u16*)alloc(MCb);      // region reserved (gf spans it)
    u16* vt = (u16*)alloc(MCb);
    float* x  = (float*)alloc((size_t)Mm*Cc*4);
    float* x2 = (float*)alloc((size_t)Mm*Cc*4);
    u16* ctx = qn;   // aliases (lifetimes disjoint)
    u16* h   = qp;
    u16* gf  = vp;   // [4096][1408] bf16 spans vp+part of vt (after fattn)

    dim3 blk(256);
    // merged prep + LN(q/k): 8192 LN blocks + 5456 prep blocks
    prepln_k<<<2*Mm + 5456, blk, 0, stream>>>(query, key, g_q, b_q, g_k, b_k, qn, kn,
                                              in_proj_w, wA, proj_w, wPb, w1, w1b, w2, w2b,
                                              w3, w3b, out_w, wOt, out_b, proj_b, bc, rel_table, mr);

    // QKV projections + Wc fold + V-transpose: 1664-block XCD-chunked grid (64-row tiles)
    mqkv_k<<<1664, blk, 0, stream>>>(qn, kn, wA, in_proj_b, qp, wPb, wOt, wCb, vt);

    fattn_k<<<Bb*Hh*16, dim3(512), 0, stream>>>(qp, kp, vt, mr, ctx);

    dim3 g1(Cc/128, Mm/64);
    mgemm64_k<0,1,1><<<g1, blk, 0, stream>>>(ctx, wCb, bc, query, x, Cc, Cc);

    ln_k<1><<<Mm, blk, 0, stream>>>(x, g_ffn, b_ffn, h);
    dim3 g2(HIDP/128, Mm/64);
    mswiglu64_k<<<g2, blk, 0, stream>>>(h, w1b, w2b, gf, HIDP, Cc);
    dim3 g3(Cc/128, Mm/64);
    mgemm64_k<0,1,0><<<g3, blk, 0, stream>>>(gf, w3b, nullptr, x, x2, Cc, HIDP);

    ln_k<0><<<Mm, blk, 0, stream>>>(x2, g_out, b_out, d_out);
}